// Round 1
// 348.765 us; speedup vs baseline: 1.0032x; 1.0032x over previous
//
#include <hip/hip_runtime.h>

#define BB 32
#define CC 384
#define TT 512
#define MAXF 6656      // T * 13
#define CG 8           // channels per block
#define XSTR 516       // padded LDS row stride in floats; 516*4 % 16 == 0, 516 % 32 == 4 (bank rotate)
#define NWG (BB * (CC / CG))   // 1536

typedef unsigned short u16;

__device__ __forceinline__ int repeat_count(float d) {
    const float fr = 44100.0f * d;
    float rf;
    if (fr - 1024.0f > 0.0f) rf = fmaxf((fr - 1024.0f) * (1.0f / 256.0f), 1.0f);
    else rf = (d == 0.0f) ? 0.0f : 1.0f;
    return (int)rf;
}

// ---------------------------------------------------------------------------
// K1: one block per batch. Scan repeat counts, build token map (sentinel 512
// for frames >= fl), dump it to global gtok, and write pitch_out + fl_out.
// ---------------------------------------------------------------------------
__global__ __launch_bounds__(256) void lr_scan_kernel(
        const float* __restrict__ notepitch,
        const float* __restrict__ duration,
        u16* __restrict__ gtok,
        float* __restrict__ pitch_out,
        float* __restrict__ fl_out) {
    __shared__ __attribute__((aligned(16))) u16 stok[MAXF];   // 13 KB
    __shared__ float snp[TT];                                 // 2 KB
    __shared__ int   sbuf[256];                               // 1 KB

    const int b = blockIdx.x;
    const int tid = threadIdx.x;

    const float2 dp  = *(const float2*)(duration  + b * TT + 2 * tid);
    const float2 np2 = *(const float2*)(notepitch + b * TT + 2 * tid);
    const int r0 = repeat_count(dp.x);
    const int r1 = repeat_count(dp.y);
    const int s  = r0 + r1;

    // inclusive scan over 256 pair-sums
    sbuf[tid] = s;
    __syncthreads();
    for (int off = 1; off < 256; off <<= 1) {
        const int add = (tid >= off) ? sbuf[tid - off] : 0;
        __syncthreads();
        sbuf[tid] += add;
        __syncthreads();
    }
    const int incl = sbuf[tid];      // cum[2*tid+1]
    const int excl = incl - s;       // start frame of token 2*tid
    const int fl   = sbuf[255];

    *(float2*)(snp + 2 * tid) = np2;
    if (tid == 0) fl_out[b] = (float)fl;

    // scatter inversion: token t owns frames [cum[t-1], cum[t])
    for (int f = excl;      f < excl + r0; ++f) stok[f] = (u16)(2 * tid);
    for (int f = excl + r0; f < incl;      ++f) stok[f] = (u16)(2 * tid + 1);
    // sentinel for invalid frames -> points at the LDS zero slot in K2
    for (int f = fl + tid; f < MAXF; f += 256) stok[f] = (u16)TT;
    __syncthreads();

    // vectorized token dump: MAXF*2 B = 832 x 16 B
    {
        const uint4* s4 = (const uint4*)stok;
        uint4* g4 = (uint4*)(gtok + (size_t)b * MAXF);
        #pragma unroll
        for (int k = 0; k < 4; ++k) {
            const int i = k * 256 + tid;
            if (i < MAXF / 8) g4[i] = s4[i];
        }
    }

    // pitch: (float)(int)notepitch[tok], 0 for sentinel
    float* const pb = pitch_out + (size_t)b * MAXF;
    #pragma unroll
    for (int k = 0; k < 7; ++k) {
        const int i = k * 256 + tid;       // float4 index
        if (i < MAXF / 4) {
            const int f = i * 4;
            const int t0 = stok[f], t1 = stok[f + 1];
            const int t2 = stok[f + 2], t3 = stok[f + 3];
            float4 pv;
            pv.x = (t0 < TT) ? (float)(int)snp[t0] : 0.f;
            pv.y = (t1 < TT) ? (float)(int)snp[t1] : 0.f;
            pv.z = (t2 < TT) ? (float)(int)snp[t2] : 0.f;
            pv.w = (t3 < TT) ? (float)(int)snp[t3] : 0.f;
            *(float4*)(pb + f) = pv;
        }
    }
}

// ---------------------------------------------------------------------------
// K2: pure streamer. 8 channels per block, padded LDS with zero slot at
// index 512 so sentinel tokens gather 0.0 — no masks, no phases, 1 barrier.
// ---------------------------------------------------------------------------
__global__ __launch_bounds__(256) void lr_write_kernel(
        const float* __restrict__ x,
        const u16* __restrict__ gtok,
        float* __restrict__ out) {
    __shared__ float xs[CG * XSTR];   // 16.5 KB

    const int tid = threadIdx.x;
    // XCD-chunked swizzle: 192 consecutive logical blocks (4 batches) per XCD
    // so each XCD's L2 only caches 4 batches' worth of gtok. NWG % 8 == 0.
    const int wg  = blockIdx.x;
    const int swz = (wg & 7) * (NWG / 8) + (wg >> 3);
    const int b   = swz / (CC / CG);
    const int cg  = swz % (CC / CG);

    // x staging loads (in flight during token prefetch)
    const float4* xsrc = (const float4*)(x + ((size_t)(b * CC + cg * CG)) * TT);
    const float4 xa0 = xsrc[tid];
    const float4 xa1 = xsrc[256 + tid];
    const float4 xa2 = xsrc[512 + tid];
    const float4 xa3 = xsrc[768 + tid];

    // prefetch all 7 chunks of tokens (issued after x loads: in-order vmcnt
    // means waiting on these never waits on the younger stores below)
    const uint2* tsrc = (const uint2*)(gtok + (size_t)b * MAXF);
    uint2 tk[7];
    #pragma unroll
    for (int ch = 0; ch < 7; ++ch) {
        const int i = ch * 256 + tid;                    // uint2 index = frame/4
        tk[ch] = (i < MAXF / 4) ? tsrc[i]
                                : make_uint2(0x02000200u, 0x02000200u);
    }

    // stage x into padded LDS rows
    #pragma unroll
    for (int j = 0; j < 4; ++j) {
        const int i = j * 256 + tid;                     // float4 id in [0,1024)
        const float4 v = (j == 0) ? xa0 : (j == 1) ? xa1 : (j == 2) ? xa2 : xa3;
        *(float4*)(xs + (i >> 7) * XSTR + (i & 127) * 4) = v;
    }
    if (tid < CG) xs[tid * XSTR + TT] = 0.f;             // zero slot (index 512)
    __syncthreads();

    float* const obase = out + ((size_t)(b * CC + cg * CG)) * MAXF;
    #pragma unroll
    for (int ch = 0; ch < 7; ++ch) {
        const int p0 = ch * 1024 + tid * 4;
        if (ch < 6 || tid < 128) {                       // last chunk is half
            const int u0 = tk[ch].x & 0xFFFF;
            const int u1 = tk[ch].x >> 16;
            const int u2 = tk[ch].y & 0xFFFF;
            const int u3 = tk[ch].y >> 16;
            #pragma unroll
            for (int c = 0; c < CG; ++c) {
                const float* xr = xs + c * XSTR;
                *(float4*)(obase + (size_t)c * MAXF + p0) =
                    make_float4(xr[u0], xr[u1], xr[u2], xr[u3]);
            }
        }
    }
}

// ---------------------------------------------------------------------------
// Fallback: previous fused single-kernel (used only if workspace too small).
// ---------------------------------------------------------------------------
#define NCHUNK 7
__global__ __launch_bounds__(256) void lr_fused_kernel(
        const float* __restrict__ x,
        const float* __restrict__ notepitch,
        const float* __restrict__ duration,
        float* __restrict__ out,
        float* __restrict__ pitch_out,
        float* __restrict__ fl_out) {
    __shared__ float xs[CG * TT];
    __shared__ float snp[TT];
    __shared__ int   sbuf[256];
    __shared__ __attribute__((aligned(16))) u16 stok[MAXF];

    const int b   = blockIdx.y;
    const int cg  = blockIdx.x;
    const int tid = threadIdx.x;
    const bool do_pitch = (cg == 0);

    const float4* xsrc = (const float4*)(x + ((size_t)(b * CC + cg * CG)) * TT);
    const float4 xa0 = xsrc[tid];
    const float4 xa1 = xsrc[256 + tid];
    const float4 xa2 = xsrc[512 + tid];
    const float4 xa3 = xsrc[768 + tid];
    float2 np2 = make_float2(0.f, 0.f);
    if (do_pitch) np2 = *(const float2*)(notepitch + b * TT + 2 * tid);

    const float2 dp = *(const float2*)(duration + b * TT + 2 * tid);
    const int r0 = repeat_count(dp.x);
    const int r1 = repeat_count(dp.y);
    const int s = r0 + r1;

    sbuf[tid] = s;
    __syncthreads();
    for (int off = 1; off < 256; off <<= 1) {
        const int add = (tid >= off) ? sbuf[tid - off] : 0;
        __syncthreads();
        sbuf[tid] += add;
        __syncthreads();
    }
    const int incl = sbuf[tid];
    const int excl = incl - s;
    const int fl   = sbuf[255];

    if (do_pitch && tid == 0) fl_out[b] = (float)fl;

    {
        float4* xdst = (float4*)xs;
        xdst[tid] = xa0; xdst[256 + tid] = xa1;
        xdst[512 + tid] = xa2; xdst[768 + tid] = xa3;
    }
    if (do_pitch) *(float2*)(snp + 2 * tid) = np2;

    float* const obase = out + ((size_t)(b * CC + cg * CG)) * MAXF;
    const float4 z = make_float4(0.f, 0.f, 0.f, 0.f);

    #pragma unroll
    for (int ch = 0; ch < NCHUNK; ++ch) {
        const int base = ch * 1024;
        const int p0 = base + tid * 4;
        if (base >= fl && p0 < MAXF) {
            #pragma unroll
            for (int c = 0; c < CG; ++c)
                *(float4*)(obase + (size_t)c * MAXF + p0) = z;
            if (do_pitch)
                *(float4*)(pitch_out + (size_t)b * MAXF + p0) = z;
        }
    }

    for (int f = excl; f < excl + r0; ++f)       stok[f] = (u16)(2 * tid);
    for (int f = excl + r0; f < incl; ++f)       stok[f] = (u16)(2 * tid + 1);
    __syncthreads();

    for (int ch = 0; ch < NCHUNK; ++ch) {
        const int base = ch * 1024;
        const int p0 = base + tid * 4;
        if (base >= fl || p0 >= MAXF) continue;

        if (base + 1024 <= fl) {
            const ushort4 tks = *(const ushort4*)(stok + p0);
            const int u0 = tks.x, u1 = tks.y, u2 = tks.z, u3 = tks.w;
            #pragma unroll
            for (int c = 0; c < CG; ++c) {
                const float* xr = xs + c * TT;
                *(float4*)(obase + (size_t)c * MAXF + p0) =
                    make_float4(xr[u0], xr[u1], xr[u2], xr[u3]);
            }
            if (do_pitch)
                *(float4*)(pitch_out + (size_t)b * MAXF + p0) =
                    make_float4((float)(int)snp[u0], (float)(int)snp[u1],
                                (float)(int)snp[u2], (float)(int)snp[u3]);
        } else {
            const ushort4 tks = *(const ushort4*)(stok + p0);
            const int u0 = min((int)tks.x, TT - 1), u1 = min((int)tks.y, TT - 1);
            const int u2 = min((int)tks.z, TT - 1), u3 = min((int)tks.w, TT - 1);
            const bool m0 = p0 < fl, m1 = p0 + 1 < fl;
            const bool m2 = p0 + 2 < fl, m3 = p0 + 3 < fl;
            #pragma unroll
            for (int c = 0; c < CG; ++c) {
                const float* xr = xs + c * TT;
                float4 v;
                v.x = m0 ? xr[u0] : 0.f;
                v.y = m1 ? xr[u1] : 0.f;
                v.z = m2 ? xr[u2] : 0.f;
                v.w = m3 ? xr[u3] : 0.f;
                *(float4*)(obase + (size_t)c * MAXF + p0) = v;
            }
            if (do_pitch) {
                float4 pv;
                pv.x = m0 ? (float)(int)snp[u0] : 0.f;
                pv.y = m1 ? (float)(int)snp[u1] : 0.f;
                pv.z = m2 ? (float)(int)snp[u2] : 0.f;
                pv.w = m3 ? (float)(int)snp[u3] : 0.f;
                *(float4*)(pitch_out + (size_t)b * MAXF + p0) = pv;
            }
        }
    }
}

extern "C" void kernel_launch(void* const* d_in, const int* in_sizes, int n_in,
                              void* d_out, int out_size, void* d_ws, size_t ws_size,
                              hipStream_t stream) {
    const float* x         = (const float*)d_in[0];  // (B, C, T)
    const float* notepitch = (const float*)d_in[1];  // (B, T)
    const float* duration  = (const float*)d_in[2];  // (B, T)
    // d_in[3] = x_lengths — unused by the reference computation

    float* out       = (float*)d_out;                    // (B, C, MAXF)
    float* pitch_out = out + (size_t)BB * CC * MAXF;     // (B, MAXF)
    float* fl_out    = pitch_out + (size_t)BB * MAXF;    // (B,)

    const size_t gtok_bytes = (size_t)BB * MAXF * sizeof(u16);   // 426 KB
    if (d_ws != nullptr && ws_size >= gtok_bytes) {
        u16* gtok = (u16*)d_ws;
        lr_scan_kernel<<<BB, 256, 0, stream>>>(notepitch, duration,
                                               gtok, pitch_out, fl_out);
        lr_write_kernel<<<NWG, 256, 0, stream>>>(x, gtok, out);
    } else {
        dim3 g(CC / CG, BB);
        lr_fused_kernel<<<g, 256, 0, stream>>>(x, notepitch, duration,
                                               out, pitch_out, fl_out);
    }
}